// Round 7
// baseline (308.273 us; speedup 1.0000x reference)
//
#include <hip/hip_runtime.h>
#include <cstddef>
#include <cstdint>
#include <math.h>

#define S_LEN 2048
#define DIM 1024
#define NH 16
#define HD 64

typedef __attribute__((ext_vector_type(8))) short bf16x8;
typedef __attribute__((ext_vector_type(8))) unsigned short u16x8;
typedef __attribute__((ext_vector_type(4))) float f32x4;

__device__ inline unsigned short f2bf(float x) {
  union { float f; unsigned u; } v; v.f = x;
  unsigned r = v.u + 0x7FFFu + ((v.u >> 16) & 1u);   // round-to-nearest-even
  return (unsigned short)(r >> 16);
}
__device__ inline float bf2f(unsigned short x) {
  union { unsigned u; float f; } v; v.u = ((unsigned)x) << 16; return v.f;
}

#define GLOAD_LDS16(g, l)                                              \
  __builtin_amdgcn_global_load_lds(                                    \
      (const __attribute__((address_space(1))) void*)(g),              \
      (__attribute__((address_space(3))) void*)(l), 16, 0, 0)

// ---------------------------------------------------------------------------
// fp32 -> bf16 conversion; fold[y]=1 additionally applies the entanglement
// head-mix to weight rows: dst[x*64+d][k] = sum_h E[h][x] * src[h*64+d][k].
// (RoPE commutes with the head-mix since all heads share the same per-(s,j)
// rotation, so entangle can be absorbed into Wq/Wk before the GEMM.)
// ---------------------------------------------------------------------------
struct ConvBatch {
  const float* src[10];
  unsigned short* dst[10];
  int n[10];
  int fold[10];
};

__global__ __launch_bounds__(256) void conv_kernel(ConvBatch cb,
                                                   const float* __restrict__ E)
{
  __shared__ float Es[NH * NH];
  const int t = threadIdx.x;
  Es[t] = E[t];
  __syncthreads();

  const int y = blockIdx.y;
  const int flat = (blockIdx.x * 256 + t) * 8;
  if (flat >= cb.n[y]) return;
  const float* s = cb.src[y];

  if (!cb.fold[y]) {
    float4 a = *(const float4*)(s + flat);
    float4 b = *(const float4*)(s + flat + 4);
    u16x8 o;
    o[0] = f2bf(a.x); o[1] = f2bf(a.y); o[2] = f2bf(a.z); o[3] = f2bf(a.w);
    o[4] = f2bf(b.x); o[5] = f2bf(b.y); o[6] = f2bf(b.z); o[7] = f2bf(b.w);
    *(u16x8*)(cb.dst[y] + flat) = o;
  } else {
    const int row = flat >> 10;       // output row = x*64+d
    const int k0  = flat & 1023;
    const int x = row >> 6, d = row & 63;
    float acc[8] = {};
#pragma unroll
    for (int h = 0; h < NH; h++) {
      const float e = Es[h * NH + x];
      const float* p = s + ((size_t)((h << 6) + d) << 10) + k0;
      float4 a = *(const float4*)p;
      float4 b = *(const float4*)(p + 4);
      acc[0] += e * a.x; acc[1] += e * a.y; acc[2] += e * a.z; acc[3] += e * a.w;
      acc[4] += e * b.x; acc[5] += e * b.y; acc[6] += e * b.z; acc[7] += e * b.w;
    }
    u16x8 o;
#pragma unroll
    for (int j = 0; j < 8; j++) o[j] = f2bf(acc[j]);
    *(u16x8*)(cb.dst[y] + flat) = o;
  }
}

// ---------------------------------------------------------------------------
// Fold biases through the entanglement mix: b'[x*64+d] = sum_h E[h,x] b[h*64+d]
// ---------------------------------------------------------------------------
__global__ __launch_bounds__(256) void bias_fold_kernel(
    const float* __restrict__ b0, const float* __restrict__ b1,
    const float* __restrict__ b2, const float* __restrict__ b3,
    const float* __restrict__ E, float* __restrict__ out)
{
  __shared__ float Es[NH * NH];
  const int t = threadIdx.x;
  Es[t] = E[t];
  __syncthreads();
  const float* srcs[4] = {b0, b1, b2, b3};
  for (int idx = t; idx < 4096; idx += 256) {
    const int tz = idx >> 10, nn = idx & 1023;
    const int x = nn >> 6, d = nn & 63;
    const float* b = srcs[tz];
    float acc = 0.f;
#pragma unroll
    for (int h = 0; h < NH; h++) acc += Es[h * NH + x] * b[h * 64 + d];
    out[idx] = acc;
  }
}

// ---------------------------------------------------------------------------
// Precompute rope cos/sin table [s][j] (2048x16) and phase table [x*64+d].
// ---------------------------------------------------------------------------
__global__ __launch_bounds__(256) void prep_tabs_kernel(
    const float* __restrict__ freqs, const float* __restrict__ phase,
    float2* __restrict__ ropeTab, float2* __restrict__ phaseTab)
{
  const int idx = blockIdx.x * 256 + threadIdx.x;
  if (idx < 32768) {
    const int s = idx >> 4, j = idx & 15;
    float sn, cs;
    sincosf((float)s * freqs[j], &sn, &cs);
    ropeTab[idx] = make_float2(cs, sn);
  } else if (idx < 32768 + 1024) {
    const int k = idx - 32768;
    float sn, cs;
    sincosf(phase[k], &sn, &cs);
    phaseTab[k] = make_float2(cs, sn);
  }
}

// ---------------------------------------------------------------------------
// bf16 MFMA GEMM: C = A @ W^T + bias, m97 structure (128x128, BK=32,
// global_load_lds w=16). Per-z output mode:
//   0: fp32 row-major (s, DIM)
//   1: bf16 head-major [h][s][d]
//   2: bf16 transposed head-major [h][d][s]   (for V)
// ---------------------------------------------------------------------------
struct BGemm {
  const unsigned short* A[6];
  const unsigned short* W[6];
  const float* bias[6];
  void* C[6];
  int mode[6];
};

__global__ __launch_bounds__(256) void gemm_mfma_kernel(BGemm gb)
{
  constexpr int K = DIM;
  const int z = blockIdx.z;
  const unsigned short* __restrict__ A = gb.A[z];
  const unsigned short* __restrict__ W = gb.W[z];
  const float* __restrict__ bias = gb.bias[z];
  const int mode = gb.mode[z];

  __shared__ __align__(16) unsigned short As[128 * 32];
  __shared__ __align__(16) unsigned short Ws[128 * 32];

  const int t    = threadIdx.x;
  const int lane = t & 63;
  const int w    = t >> 6;
  const int wm   = w >> 1, wn = w & 1;
  const int quad = lane >> 4, lcol = lane & 15;
  const int m0   = blockIdx.y * 128;
  const int n0   = blockIdx.x * 128;

  const int srow = t >> 2;
  const int sk8  = (t & 3) * 8;

  f32x4 acc[4][4];
#pragma unroll
  for (int i = 0; i < 4; i++)
#pragma unroll
    for (int j = 0; j < 4; j++)
#pragma unroll
      for (int r = 0; r < 4; r++) acc[i][j][r] = 0.f;

  for (int k0 = 0; k0 < K; k0 += 32) {
    __syncthreads();
#pragma unroll
    for (int p = 0; p < 2; p++) {
      const unsigned short* ga = A + (size_t)(m0 + p * 64 + srow) * K + k0 + sk8;
      GLOAD_LDS16(ga, As + (size_t)(p * 256 + w * 64) * 8);
      const unsigned short* gw = W + (size_t)(n0 + p * 64 + srow) * K + k0 + sk8;
      GLOAD_LDS16(gw, Ws + (size_t)(p * 256 + w * 64) * 8);
    }
    __syncthreads();

    bf16x8 af[4], bfr[4];
#pragma unroll
    for (int mi = 0; mi < 4; mi++)
      af[mi] = *(const bf16x8*)&As[(wm * 64 + mi * 16 + lcol) * 32 + quad * 8];
#pragma unroll
    for (int ni = 0; ni < 4; ni++)
      bfr[ni] = *(const bf16x8*)&Ws[(wn * 64 + ni * 16 + lcol) * 32 + quad * 8];
#pragma unroll
    for (int mi = 0; mi < 4; mi++)
#pragma unroll
      for (int ni = 0; ni < 4; ni++)
        acc[mi][ni] = __builtin_amdgcn_mfma_f32_16x16x32_bf16(af[mi], bfr[ni], acc[mi][ni], 0, 0, 0);
  }

#pragma unroll
  for (int mi = 0; mi < 4; mi++) {
#pragma unroll
    for (int ni = 0; ni < 4; ni++) {
#pragma unroll
      for (int r = 0; r < 4; r++) {
        const int grow = m0 + wm * 64 + mi * 16 + quad * 4 + r;
        const int gcol = n0 + wn * 64 + ni * 16 + lcol;
        const float v = acc[mi][ni][r] + bias[gcol];
        if (mode == 0) {
          ((float*)gb.C[z])[(size_t)grow * DIM + gcol] = v;
        } else if (mode == 1) {
          const int hh = gcol >> 6, d = gcol & 63;
          ((unsigned short*)gb.C[z])[((size_t)hh * S_LEN + grow) * HD + d] = f2bf(v);
        } else {
          const int hh = gcol >> 6, d = gcol & 63;
          ((unsigned short*)gb.C[z])[((size_t)hh * HD + d) * S_LEN + grow] = f2bf(v);
        }
      }
    }
  }
}

// ---------------------------------------------------------------------------
// Fused RoPE + phase rotation, in-place on (q_r,q_i) or (k_r,k_i).
// Entanglement is already folded into the weights, so tensors here are the
// post-mix values; rope commutes with the mix, phase comes last as in ref.
// ---------------------------------------------------------------------------
__global__ __launch_bounds__(256) void ropephase_kernel(
    unsigned short* q_r, unsigned short* q_i,
    unsigned short* k_r, unsigned short* k_i,
    const float2* __restrict__ ropeTab, const float2* __restrict__ phaseTab)
{
  const int z = blockIdx.y;
  unsigned short* R = z ? k_r : q_r;
  unsigned short* I = z ? k_i : q_i;

  const int flat = blockIdx.x * 256 + threadIdx.x;   // 0..262143
  const int x   = flat >> 14;
  const int rem = flat & 16383;
  const int s   = rem >> 3;
  const int d0  = (rem & 7) * 8;

  const size_t base = ((size_t)x * S_LEN + s) * HD + d0;
  bf16x8 r8 = *(const bf16x8*)(R + base);
  bf16x8 i8 = *(const bf16x8*)(I + base);
  float a[8], b[8];
#pragma unroll
  for (int e = 0; e < 8; e++) {
    a[e] = bf2f((unsigned short)r8[e]);
    b[e] = bf2f((unsigned short)i8[e]);
  }

  if (d0 < 32) {
#pragma unroll
    for (int jj = 0; jj < 8; jj += 2) {
      const int j = (d0 + jj) >> 1;
      const float2 cs = ropeTab[s * 16 + j];
      const float a1 = a[jj], a2 = a[jj + 1];
      const float b1 = b[jj], b2 = b[jj + 1];
      a[jj]     = a1 * cs.x - a2 * cs.y;
      a[jj + 1] = a1 * cs.y + a2 * cs.x;
      b[jj]     = b1 * cs.x - b2 * cs.y;
      b[jj + 1] = b1 * cs.y + b2 * cs.x;
    }
  }

  u16x8 orr, oii;
#pragma unroll
  for (int e = 0; e < 8; e++) {
    const float2 pp = phaseTab[x * HD + d0 + e];
    orr[e] = f2bf(a[e] * pp.x - b[e] * pp.y);
    oii[e] = f2bf(a[e] * pp.y + b[e] * pp.x);
  }
  *(u16x8*)(R + base) = orr;
  *(u16x8*)(I + base) = oii;
}

// ---------------------------------------------------------------------------
// Flash attention on MFMA, kv-SPLIT (flash-decoding style):
// 1024 blocks: pair p = bx>>1 (itile = 31-(p>>4) heavy-first, h = p&15),
// half = bx&1 takes kv-tiles [0,jmid) or [jmid,n).  No-max softmax makes
// halves associative: each block writes UNNORMALIZED f32 partial O and
// partial row-sums; combine_kernel sums halves and normalizes.
// Block lengths <= 16 tiles -> dynamic refill (3 resident/CU by LDS)
// balances the causal wedge.
// ---------------------------------------------------------------------------
#define LDK 72

__global__ __launch_bounds__(256) void flash_mfma_kernel(
    const unsigned short* __restrict__ Qr, const unsigned short* __restrict__ Qi,
    const unsigned short* __restrict__ Kr, const unsigned short* __restrict__ Ki,
    const unsigned short* __restrict__ VtR, const unsigned short* __restrict__ VtI,
    float* __restrict__ OpR, float* __restrict__ OpI, float* __restrict__ Lp,
    const float* __restrict__ p_is, const float* __restrict__ p_at,
    const float* __restrict__ p_ce)
{
  __shared__ __align__(16) unsigned short Krs[64 * LDK];
  __shared__ __align__(16) unsigned short Kis[64 * LDK];
  __shared__ __align__(16) unsigned short VTr[64 * LDK];
  __shared__ __align__(16) unsigned short VTi[64 * LDK];
  __shared__ __align__(16) unsigned short Ps [64 * LDK];

  const int t    = threadIdx.x;
  const int lane = t & 63;
  const int w    = t >> 6;
  const int quad = lane >> 4;
  const int lcol = lane & 15;

  const int bx    = blockIdx.x;
  const int p     = bx >> 1;
  const int half  = bx & 1;
  const int itile = 31 - (p >> 4);     // heavy-first
  const int h     = p & 15;
  const int i0    = itile * 64;
  const int n     = itile + 1;
  const int jmid  = (n + 1) >> 1;
  const int jbeg  = half ? jmid : 0;
  const int jend  = half ? n : jmid;

  const float strength = 1.f / (1.f + expf(-p_is[0]));
  const float temp     = fmaxf(expf(p_at[0]), 0.1f);
  const float cfac     = strength / temp;
  const float eps      = 0.03f / (1.f + expf(-p_ce[0]));
  const float c2       = 0.015625f * (1.f + eps * eps);  // scale^2*(1+eps^2)

  const int srow = t >> 3;
  const int sd0  = (t & 7) * 8;

  // Q fragments straight from global bf16
  bf16x8 qrf[2], qif[2];
  {
    const int qrow = i0 + w * 16 + lcol;
    const size_t base_q = ((size_t)h * S_LEN + qrow) * HD;
#pragma unroll
    for (int ks = 0; ks < 2; ks++) {
      qrf[ks] = *(const bf16x8*)(Qr + base_q + ks * 32 + quad * 8);
      qif[ks] = *(const bf16x8*)(Qi + base_q + ks * 32 + quad * 8);
    }
  }

  float lsum[4] = {0.f, 0.f, 0.f, 0.f};
  f32x4 aOr[4], aOi[4];
#pragma unroll
  for (int cc = 0; cc < 4; cc++)
#pragma unroll
    for (int r = 0; r < 4; r++) { aOr[cc][r] = 0.f; aOi[cc][r] = 0.f; }

  bf16x8 pk[2], pki[2], pv[2], pvi[2];

  if (jbeg < jend) {
    const int j0 = jbeg * 64;
    const size_t kb = ((size_t)h * S_LEN + j0) * HD;
#pragma unroll
    for (int it = 0; it < 2; it++) {
      const int row = srow + it * 32;
      pk [it] = *(const bf16x8*)(Kr  + kb + (size_t)row * HD + sd0);
      pki[it] = *(const bf16x8*)(Ki  + kb + (size_t)row * HD + sd0);
      pv [it] = *(const bf16x8*)(VtR + ((size_t)h * HD + row) * S_LEN + j0 + sd0);
      pvi[it] = *(const bf16x8*)(VtI + ((size_t)h * HD + row) * S_LEN + j0 + sd0);
    }
  }

  for (int jt = jbeg; jt < jend; jt++) {
    __syncthreads();
#pragma unroll
    for (int it = 0; it < 2; it++) {
      const int row = srow + it * 32;
      *(bf16x8*)&Krs[row * LDK + sd0] = pk [it];
      *(bf16x8*)&Kis[row * LDK + sd0] = pki[it];
      *(bf16x8*)&VTr[row * LDK + sd0] = pv [it];
      *(bf16x8*)&VTi[row * LDK + sd0] = pvi[it];
    }
    __syncthreads();

    if (jt + 1 < jend) {
      const int j0n = (jt + 1) * 64;
      const size_t kb = ((size_t)h * S_LEN + j0n) * HD;
#pragma unroll
      for (int it = 0; it < 2; it++) {
        const int row = srow + it * 32;
        pk [it] = *(const bf16x8*)(Kr  + kb + (size_t)row * HD + sd0);
        pki[it] = *(const bf16x8*)(Ki  + kb + (size_t)row * HD + sd0);
        pv [it] = *(const bf16x8*)(VtR + ((size_t)h * HD + row) * S_LEN + j0n + sd0);
        pvi[it] = *(const bf16x8*)(VtI + ((size_t)h * HD + row) * S_LEN + j0n + sd0);
      }
    }

    // ---- scores ----
    f32x4 k1[4], k2[4], kx[4];
#pragma unroll
    for (int cc = 0; cc < 4; cc++)
#pragma unroll
      for (int r = 0; r < 4; r++) { k1[cc][r] = 0.f; k2[cc][r] = 0.f; kx[cc][r] = 0.f; }
#pragma unroll
    for (int ks = 0; ks < 2; ks++) {
#pragma unroll
      for (int cc = 0; cc < 4; cc++) {
        const int off = (cc * 16 + lcol) * LDK + ks * 32 + quad * 8;
        bf16x8 krf = *(const bf16x8*)&Krs[off];
        bf16x8 kif = *(const bf16x8*)&Kis[off];
        k1[cc] = __builtin_amdgcn_mfma_f32_16x16x32_bf16(qrf[ks], krf, k1[cc], 0, 0, 0);
        k2[cc] = __builtin_amdgcn_mfma_f32_16x16x32_bf16(qif[ks], kif, k2[cc], 0, 0, 0);
        kx[cc] = __builtin_amdgcn_mfma_f32_16x16x32_bf16(qrf[ks], kif, kx[cc], 0, 0, 0);
        kx[cc] = __builtin_amdgcn_mfma_f32_16x16x32_bf16(qif[ks], krf, kx[cc], 0, 0, 0);
      }
    }

    // ---- no-max softmax ----
    const bool diag = (jt == itile);
    const int j0 = jt * 64;
#pragma unroll
    for (int r = 0; r < 4; r++) {
      const int prow = (w * 16 + quad * 4 + r) * LDK;
      float rs = 0.f;
#pragma unroll
      for (int cc = 0; cc < 4; cc++) {
        const float a = k1[cc][r] - k2[cc][r];
        const float b = kx[cc][r];
        const float u = fmaf(b, b, a * a);
        const float mag = sqrtf(fmaf(u, c2, 1e-6f));
        float pp = __expf(mag * cfac);
        if (diag) {
          const int gi = i0 + w * 16 + quad * 4 + r;
          const int gj = j0 + cc * 16 + lcol;
          if (gj > gi) pp = 0.f;
        }
        Ps[prow + cc * 16 + lcol] = f2bf(pp);
        rs += pp;
      }
      lsum[r] += rs;
    }

    // ---- PV ----
#pragma unroll
    for (int ks = 0; ks < 2; ks++) {
      bf16x8 pf = *(const bf16x8*)&Ps[(w * 16 + lcol) * LDK + ks * 32 + quad * 8];
#pragma unroll
      for (int cc = 0; cc < 4; cc++) {
        const int off = (cc * 16 + lcol) * LDK + ks * 32 + quad * 8;
        bf16x8 vrf = *(const bf16x8*)&VTr[off];
        bf16x8 vif = *(const bf16x8*)&VTi[off];
        aOr[cc] = __builtin_amdgcn_mfma_f32_16x16x32_bf16(pf, vrf, aOr[cc], 0, 0, 0);
        aOi[cc] = __builtin_amdgcn_mfma_f32_16x16x32_bf16(pf, vif, aOi[cc], 0, 0, 0);
      }
    }
  }

  // ---- epilogue: write UNNORMALIZED partials + row sums ----
  const size_t SLsz = (size_t)S_LEN * DIM;
#pragma unroll
  for (int r = 0; r < 4; r++) {
    float rs = lsum[r];
#pragma unroll
    for (int off = 1; off < 16; off <<= 1)
      rs += __shfl_xor(rs, off, 16);
    const int row = i0 + w * 16 + quad * 4 + r;
    if (lcol == 0)
      Lp[((size_t)half * NH + h) * S_LEN + row] = rs;
  }
#pragma unroll
  for (int cc = 0; cc < 4; cc++) {
#pragma unroll
    for (int r = 0; r < 4; r++) {
      const int row = i0 + w * 16 + quad * 4 + r;
      const int col = h * HD + cc * 16 + lcol;
      OpR[half * SLsz + (size_t)row * DIM + col] = aOr[cc][r];
      OpI[half * SLsz + (size_t)row * DIM + col] = aOi[cc][r];
    }
  }
}

// ---------------------------------------------------------------------------
// Combine kv-split halves: O = (O0+O1)/(L0+L1), write bf16 row-major.
// ---------------------------------------------------------------------------
__global__ __launch_bounds__(256) void combine_kernel(
    const float* __restrict__ OpR, const float* __restrict__ OpI,
    const float* __restrict__ Lp,
    unsigned short* __restrict__ Or, unsigned short* __restrict__ Oi)
{
  const size_t SLsz = (size_t)S_LEN * DIM;
  const int idx = blockIdx.x * 256 + threadIdx.x;   // 512K threads x 4 elems
  const size_t e0 = (size_t)idx * 4;
  const int s = (int)(e0 >> 10);
  const int col = (int)(e0 & 1023);
  const int h = col >> 6;

  const float L = Lp[(size_t)h * S_LEN + s] + Lp[((size_t)NH + h) * S_LEN + s];
  const float inv = 1.f / L;

  float4 r0 = *(const float4*)(OpR + e0);
  float4 r1 = *(const float4*)(OpR + SLsz + e0);
  float4 i0 = *(const float4*)(OpI + e0);
  float4 i1 = *(const float4*)(OpI + SLsz + e0);

  ushort4 orv, oiv;
  orv.x = f2bf((r0.x + r1.x) * inv); orv.y = f2bf((r0.y + r1.y) * inv);
  orv.z = f2bf((r0.z + r1.z) * inv); orv.w = f2bf((r0.w + r1.w) * inv);
  oiv.x = f2bf((i0.x + i1.x) * inv); oiv.y = f2bf((i0.y + i1.y) * inv);
  oiv.z = f2bf((i0.z + i1.z) * inv); oiv.w = f2bf((i0.w + i1.w) * inv);
  *(ushort4*)(Or + e0) = orv;
  *(ushort4*)(Oi + e0) = oiv;
}

// ---------------------------------------------------------------------------
extern "C" void kernel_launch(void* const* d_in, const int* in_sizes, int n_in,
                              void* d_out, int out_size, void* d_ws, size_t ws_size,
                              hipStream_t stream)
{
  const float* real = (const float*)d_in[0];
  const float* imag = (const float*)d_in[1];
  const float* Wq_r = (const float*)d_in[2];
  const float* bq_r = (const float*)d_in[3];
  const float* Wk_r = (const float*)d_in[4];
  const float* bk_r = (const float*)d_in[5];
  const float* Wv_r = (const float*)d_in[6];
  const float* bv_r = (const float*)d_in[7];
  const float* Wq_i = (const float*)d_in[8];
  const float* bq_i = (const float*)d_in[9];
  const float* Wk_i = (const float*)d_in[10];
  const float* bk_i = (const float*)d_in[11];
  const float* Wv_i = (const float*)d_in[12];
  const float* bv_i = (const float*)d_in[13];
  const float* Wo_r = (const float*)d_in[14];
  const float* bo_r = (const float*)d_in[15];
  const float* Wo_i = (const float*)d_in[16];
  const float* bo_i = (const float*)d_in[17];
  const float* phase = (const float*)d_in[18];
  const float* ent   = (const float*)d_in[19];
  const float* freqs = (const float*)d_in[20];
  const float* p_is  = (const float*)d_in[21];
  const float* p_at  = (const float*)d_in[22];
  const float* p_ce  = (const float*)d_in[23];

  unsigned short* ws = (unsigned short*)d_ws;
  const size_t SL = (size_t)S_LEN * DIM;   // 2M elements
  const size_t WL = (size_t)DIM * DIM;     // 1M elements

  unsigned short* realb = ws;
  unsigned short* imagb = realb + SL;
  unsigned short* Wb    = imagb + SL;        // 8 x WL
  unsigned short* q_r   = Wb + 8 * WL;
  unsigned short* k_r   = q_r + SL;
  unsigned short* v_r   = k_r + SL;          // [h][d][s]
  unsigned short* q_i   = v_r + SL;
  unsigned short* k_i   = q_i + SL;
  unsigned short* v_i   = k_i + SL;          // [h][d][s]

  float* fbase   = (float*)(v_i + SL);
  float* biasf   = fbase;                    // 4096
  float* ropeTab = biasf + 4096;             // 32768 float2 = 65536 f
  float* phaseTb = ropeTab + 65536;          // 1024 float2 = 2048 f
  float* OpR     = phaseTb + 2048;           // 2 * SL
  float* OpI     = OpR + 2 * SL;             // 2 * SL
  float* Lp      = OpI + 2 * SL;             // 2 * NH * S_LEN

  unsigned short* O_r = q_r;   // reuse after flash
  unsigned short* O_i = q_i;

  float* out_r = (float*)d_out;
  float* out_i = out_r + SL;

  // 0a. fp32->bf16 conversion (+ entangle-fold for Wq/Wk)
  ConvBatch cb;
  cb.src[0] = real; cb.dst[0] = realb; cb.n[0] = (int)SL; cb.fold[0] = 0;
  cb.src[1] = imag; cb.dst[1] = imagb; cb.n[1] = (int)SL; cb.fold[1] = 0;
  const float* wsrc[8] = {Wq_r, Wk_r, Wv_r, Wq_i, Wk_i, Wv_i, Wo_r, Wo_i};
  const int wfold[8]   = {1,    1,    0,    1,    1,    0,    0,    0};
  for (int i = 0; i < 8; i++) {
    cb.src[2 + i] = wsrc[i];
    cb.dst[2 + i] = Wb + (size_t)i * WL;
    cb.n[2 + i] = (int)WL;
    cb.fold[2 + i] = wfold[i];
  }
  conv_kernel<<<dim3(1024, 10), dim3(256), 0, stream>>>(cb, ent);

  // 0b. folded biases (bq_r', bk_r', bq_i', bk_i')
  bias_fold_kernel<<<dim3(1), dim3(256), 0, stream>>>(bq_r, bk_r, bq_i, bk_i, ent, biasf);

  // 0c. rope/phase tables
  prep_tabs_kernel<<<dim3(132), dim3(256), 0, stream>>>(
      freqs, phase, (float2*)ropeTab, (float2*)phaseTb);

  // 1. six projections (entangle pre-folded for q/k); V transposed
  BGemm g1;
  g1.A[0] = realb; g1.A[1] = realb; g1.A[2] = realb;
  g1.A[3] = imagb; g1.A[4] = imagb; g1.A[5] = imagb;
  for (int i = 0; i < 6; i++) g1.W[i] = Wb + (size_t)i * WL;
  g1.bias[0] = biasf;        g1.bias[1] = biasf + 1024; g1.bias[2] = bv_r;
  g1.bias[3] = biasf + 2048; g1.bias[4] = biasf + 3072; g1.bias[5] = bv_i;
  g1.C[0] = q_r; g1.C[1] = k_r; g1.C[2] = v_r;
  g1.C[3] = q_i; g1.C[4] = k_i; g1.C[5] = v_i;
  g1.mode[0] = 1; g1.mode[1] = 1; g1.mode[2] = 2;
  g1.mode[3] = 1; g1.mode[4] = 1; g1.mode[5] = 2;
  gemm_mfma_kernel<<<dim3(8, 16, 6), dim3(256), 0, stream>>>(g1);

  // 2. fused RoPE + phase, in-place on q and k
  ropephase_kernel<<<dim3(1024, 2), dim3(256), 0, stream>>>(
      q_r, q_i, k_r, k_i, (const float2*)ropeTab, (const float2*)phaseTb);

  // 3. flash attention, kv-split -> f32 partials
  flash_mfma_kernel<<<dim3(1024), dim3(256), 0, stream>>>(
      q_r, q_i, k_r, k_i, v_r, v_i, OpR, OpI, Lp, p_is, p_at, p_ce);

  // 4. combine halves -> bf16 O
  combine_kernel<<<dim3(2048), dim3(256), 0, stream>>>(OpR, OpI, Lp, O_r, O_i);

  // 5. output projections -> fp32 d_out
  BGemm g2 = {};
  g2.A[0] = O_r; g2.A[1] = O_i;
  g2.W[0] = Wb + 6 * WL; g2.W[1] = Wb + 7 * WL;
  g2.bias[0] = bo_r; g2.bias[1] = bo_i;
  g2.C[0] = out_r; g2.C[1] = out_i;
  g2.mode[0] = 0; g2.mode[1] = 0;
  gemm_mfma_kernel<<<dim3(8, 16, 2), dim3(256), 0, stream>>>(g2);
}

// Round 8
// 291.230 us; speedup vs baseline: 1.0585x; 1.0585x over previous
//
#include <hip/hip_runtime.h>
#include <cstddef>
#include <cstdint>
#include <math.h>

#define S_LEN 2048
#define DIM 1024
#define NH 16
#define HD 64

typedef __attribute__((ext_vector_type(8))) short bf16x8;
typedef __attribute__((ext_vector_type(8))) unsigned short u16x8;
typedef __attribute__((ext_vector_type(4))) float f32x4;

__device__ inline unsigned short f2bf(float x) {
  union { float f; unsigned u; } v; v.f = x;
  unsigned r = v.u + 0x7FFFu + ((v.u >> 16) & 1u);   // round-to-nearest-even
  return (unsigned short)(r >> 16);
}
__device__ inline float bf2f(unsigned short x) {
  union { unsigned u; float f; } v; v.u = ((unsigned)x) << 16; return v.f;
}

#define GLOAD_LDS16(g, l)                                              \
  __builtin_amdgcn_global_load_lds(                                    \
      (const __attribute__((address_space(1))) void*)(g),              \
      (__attribute__((address_space(3))) void*)(l), 16, 0, 0)

// ---------------------------------------------------------------------------
// conv kernel: y=0..9 fp32->bf16 (fold[y]=1 applies entanglement head-mix to
// weight rows: dst[x*64+d][k] = sum_h E[h][x] src[h*64+d][k]).
// y=10: misc precompute — rope cos/sin table, DOUBLED phase table
// (phase folds into Q only: q'k' = qk e^{2i phi}), and entangle-folded biases.
// ---------------------------------------------------------------------------
struct ConvBatch {
  const float* src[10];
  unsigned short* dst[10];
  int n[10];
  int fold[10];
};

__global__ __launch_bounds__(256) void conv_kernel(
    ConvBatch cb, const float* __restrict__ E,
    const float* __restrict__ freqs, const float* __restrict__ phase,
    const float* __restrict__ bq_r, const float* __restrict__ bk_r,
    const float* __restrict__ bq_i, const float* __restrict__ bk_i,
    float* __restrict__ biasf, float2* __restrict__ ropeTab,
    float2* __restrict__ phaseTab2)
{
  __shared__ float Es[NH * NH];
  const int t = threadIdx.x;
  Es[t] = E[t];
  __syncthreads();

  const int y = blockIdx.y;

  if (y == 10) {   // misc precompute slice
    const int idx = blockIdx.x * 256 + t;
    if (idx < 32768) {
      const int s = idx >> 4, j = idx & 15;
      float sn, cs;
      sincosf((float)s * freqs[j], &sn, &cs);
      ropeTab[idx] = make_float2(cs, sn);
    } else if (idx < 32768 + 1024) {
      const int k = idx - 32768;
      float sn, cs;
      sincosf(2.f * phase[k], &sn, &cs);
      phaseTab2[k] = make_float2(cs, sn);
    } else if (idx < 32768 + 1024 + 4096) {
      const int i = idx - 33792;
      const int tz = i >> 10, nn = i & 1023;
      const int x = nn >> 6, d = nn & 63;
      const float* b = (tz == 0) ? bq_r : (tz == 1) ? bk_r : (tz == 2) ? bq_i : bk_i;
      float acc = 0.f;
#pragma unroll
      for (int h = 0; h < NH; h++) acc += Es[h * NH + x] * b[h * 64 + d];
      biasf[i] = acc;
    }
    return;
  }

  const int flat = (blockIdx.x * 256 + t) * 8;
  if (flat >= cb.n[y]) return;
  const float* s = cb.src[y];

  if (!cb.fold[y]) {
    float4 a = *(const float4*)(s + flat);
    float4 b = *(const float4*)(s + flat + 4);
    u16x8 o;
    o[0] = f2bf(a.x); o[1] = f2bf(a.y); o[2] = f2bf(a.z); o[3] = f2bf(a.w);
    o[4] = f2bf(b.x); o[5] = f2bf(b.y); o[6] = f2bf(b.z); o[7] = f2bf(b.w);
    *(u16x8*)(cb.dst[y] + flat) = o;
  } else {
    const int row = flat >> 10;
    const int k0  = flat & 1023;
    const int x = row >> 6, d = row & 63;
    float acc[8] = {};
#pragma unroll
    for (int h = 0; h < NH; h++) {
      const float e = Es[h * NH + x];
      const float* p = s + ((size_t)((h << 6) + d) << 10) + k0;
      float4 a = *(const float4*)p;
      float4 b = *(const float4*)(p + 4);
      acc[0] += e * a.x; acc[1] += e * a.y; acc[2] += e * a.z; acc[3] += e * a.w;
      acc[4] += e * b.x; acc[5] += e * b.y; acc[6] += e * b.z; acc[7] += e * b.w;
    }
    u16x8 o;
#pragma unroll
    for (int j = 0; j < 8; j++) o[j] = f2bf(acc[j]);
    *(u16x8*)(cb.dst[y] + flat) = o;
  }
}

// ---------------------------------------------------------------------------
// bf16 MFMA GEMM: C = A @ W^T + bias. Output modes (per z):
//   0: fp32 row-major (s, DIM)
//   2: bf16 transposed head-major [h][d][s]   (V)
//   3: bf16 head-major [h][s][d] + fused RoPE (fp32, shfl_xor pair mix) (Q,K)
// ---------------------------------------------------------------------------
struct BGemm {
  const unsigned short* A[6];
  const unsigned short* W[6];
  const float* bias[6];
  void* C[6];
  int mode[6];
  const float2* ropeTab;
};

__global__ __launch_bounds__(256) void gemm_mfma_kernel(BGemm gb)
{
  constexpr int K = DIM;
  const int z = blockIdx.z;
  const unsigned short* __restrict__ A = gb.A[z];
  const unsigned short* __restrict__ W = gb.W[z];
  const float* __restrict__ bias = gb.bias[z];
  const int mode = gb.mode[z];

  __shared__ __align__(16) unsigned short As[128 * 32];
  __shared__ __align__(16) unsigned short Ws[128 * 32];

  const int t    = threadIdx.x;
  const int lane = t & 63;
  const int w    = t >> 6;
  const int wm   = w >> 1, wn = w & 1;
  const int quad = lane >> 4, lcol = lane & 15;
  const int m0   = blockIdx.y * 128;
  const int n0   = blockIdx.x * 128;

  const int srow = t >> 2;
  const int sk8  = (t & 3) * 8;

  f32x4 acc[4][4];
#pragma unroll
  for (int i = 0; i < 4; i++)
#pragma unroll
    for (int j = 0; j < 4; j++)
#pragma unroll
      for (int r = 0; r < 4; r++) acc[i][j][r] = 0.f;

  for (int k0 = 0; k0 < K; k0 += 32) {
    __syncthreads();
#pragma unroll
    for (int p = 0; p < 2; p++) {
      const unsigned short* ga = A + (size_t)(m0 + p * 64 + srow) * K + k0 + sk8;
      GLOAD_LDS16(ga, As + (size_t)(p * 256 + w * 64) * 8);
      const unsigned short* gw = W + (size_t)(n0 + p * 64 + srow) * K + k0 + sk8;
      GLOAD_LDS16(gw, Ws + (size_t)(p * 256 + w * 64) * 8);
    }
    __syncthreads();

    bf16x8 af[4], bfr[4];
#pragma unroll
    for (int mi = 0; mi < 4; mi++)
      af[mi] = *(const bf16x8*)&As[(wm * 64 + mi * 16 + lcol) * 32 + quad * 8];
#pragma unroll
    for (int ni = 0; ni < 4; ni++)
      bfr[ni] = *(const bf16x8*)&Ws[(wn * 64 + ni * 16 + lcol) * 32 + quad * 8];
#pragma unroll
    for (int mi = 0; mi < 4; mi++)
#pragma unroll
      for (int ni = 0; ni < 4; ni++)
        acc[mi][ni] = __builtin_amdgcn_mfma_f32_16x16x32_bf16(af[mi], bfr[ni], acc[mi][ni], 0, 0, 0);
  }

#pragma unroll
  for (int mi = 0; mi < 4; mi++) {
#pragma unroll
    for (int ni = 0; ni < 4; ni++) {
#pragma unroll
      for (int r = 0; r < 4; r++) {
        const int grow = m0 + wm * 64 + mi * 16 + quad * 4 + r;
        const int gcol = n0 + wn * 64 + ni * 16 + lcol;
        float v = acc[mi][ni][r] + bias[gcol];
        if (mode == 3) {
          const float vp = __shfl_xor(v, 1);   // partner column (gcol^1)
          const int d = gcol & 63;
          if (d < 32) {
            const float2 cs = gb.ropeTab[grow * 16 + (d >> 1)];
            v = (d & 1) ? (v * cs.x + vp * cs.y)    // odd: x1*s + x2*c
                        : (v * cs.x - vp * cs.y);   // even: x1*c - x2*s
          }
        }
        if (mode == 0) {
          ((float*)gb.C[z])[(size_t)grow * DIM + gcol] = v;
        } else if (mode == 2) {
          const int hh = gcol >> 6, d = gcol & 63;
          ((unsigned short*)gb.C[z])[((size_t)hh * HD + d) * S_LEN + grow] = f2bf(v);
        } else {   // mode 3
          const int hh = gcol >> 6, d = gcol & 63;
          ((unsigned short*)gb.C[z])[((size_t)hh * S_LEN + grow) * HD + d] = f2bf(v);
        }
      }
    }
  }
}

// ---------------------------------------------------------------------------
// Flash attention on MFMA, kv-split, no-max softmax.
// Q gets the DOUBLED phase rotation at load (once per block); K/V unphased.
// Ps aliases Krs (dead after QK^T) with a barrier after scores -> LDS 36.8 KB
// -> 4 blocks/CU. Partials written as bf16.
// ---------------------------------------------------------------------------
#define LDK 72

__global__ __launch_bounds__(256) void flash_mfma_kernel(
    const unsigned short* __restrict__ Qr, const unsigned short* __restrict__ Qi,
    const unsigned short* __restrict__ Kr, const unsigned short* __restrict__ Ki,
    const unsigned short* __restrict__ VtR, const unsigned short* __restrict__ VtI,
    unsigned short* __restrict__ OpR, unsigned short* __restrict__ OpI,
    float* __restrict__ Lp, const float2* __restrict__ phaseTab2,
    const float* __restrict__ p_is, const float* __restrict__ p_at,
    const float* __restrict__ p_ce)
{
  __shared__ __align__(16) unsigned short Krs[64 * LDK];
  __shared__ __align__(16) unsigned short Kis[64 * LDK];
  __shared__ __align__(16) unsigned short VTr[64 * LDK];
  __shared__ __align__(16) unsigned short VTi[64 * LDK];
  unsigned short* Ps = Krs;   // alias: Krs dead after scores (barrier-protected)

  const int t    = threadIdx.x;
  const int lane = t & 63;
  const int w    = t >> 6;
  const int quad = lane >> 4;
  const int lcol = lane & 15;

  const int bx    = blockIdx.x;
  const int p     = bx >> 1;
  const int half  = bx & 1;
  const int itile = 31 - (p >> 4);     // heavy-first
  const int h     = p & 15;
  const int i0    = itile * 64;
  const int n     = itile + 1;
  const int jmid  = (n + 1) >> 1;
  const int jbeg  = half ? jmid : 0;
  const int jend  = half ? n : jmid;

  const float strength = 1.f / (1.f + expf(-p_is[0]));
  const float temp     = fmaxf(expf(p_at[0]), 0.1f);
  const float cfac     = strength / temp;
  const float eps      = 0.03f / (1.f + expf(-p_ce[0]));
  const float c2       = 0.015625f * (1.f + eps * eps);  // scale^2*(1+eps^2)

  const int srow = t >> 3;
  const int sd0  = (t & 7) * 8;

  // Q fragments from global, with fused doubled-phase rotation (fp32 math)
  bf16x8 qrf[2], qif[2];
  {
    const int qrow = i0 + w * 16 + lcol;
    const size_t base_q = ((size_t)h * S_LEN + qrow) * HD;
#pragma unroll
    for (int ks = 0; ks < 2; ks++) {
      bf16x8 r8 = *(const bf16x8*)(Qr + base_q + ks * 32 + quad * 8);
      bf16x8 i8 = *(const bf16x8*)(Qi + base_q + ks * 32 + quad * 8);
      bf16x8 orr, oii;
#pragma unroll
      for (int j = 0; j < 8; j++) {
        const float2 ph = phaseTab2[h * HD + ks * 32 + quad * 8 + j];
        const float qr = bf2f((unsigned short)r8[j]);
        const float qi = bf2f((unsigned short)i8[j]);
        orr[j] = (short)f2bf(qr * ph.x - qi * ph.y);
        oii[j] = (short)f2bf(qr * ph.y + qi * ph.x);
      }
      qrf[ks] = orr;
      qif[ks] = oii;
    }
  }

  float lsum[4] = {0.f, 0.f, 0.f, 0.f};
  f32x4 aOr[4], aOi[4];
#pragma unroll
  for (int cc = 0; cc < 4; cc++)
#pragma unroll
    for (int r = 0; r < 4; r++) { aOr[cc][r] = 0.f; aOi[cc][r] = 0.f; }

  bf16x8 pk[2], pki[2], pv[2], pvi[2];

  if (jbeg < jend) {
    const int j0 = jbeg * 64;
    const size_t kb = ((size_t)h * S_LEN + j0) * HD;
#pragma unroll
    for (int it = 0; it < 2; it++) {
      const int row = srow + it * 32;
      pk [it] = *(const bf16x8*)(Kr  + kb + (size_t)row * HD + sd0);
      pki[it] = *(const bf16x8*)(Ki  + kb + (size_t)row * HD + sd0);
      pv [it] = *(const bf16x8*)(VtR + ((size_t)h * HD + row) * S_LEN + j0 + sd0);
      pvi[it] = *(const bf16x8*)(VtI + ((size_t)h * HD + row) * S_LEN + j0 + sd0);
    }
  }

  for (int jt = jbeg; jt < jend; jt++) {
    __syncthreads();   // prev tile's PV reads (Ps/VT) done
#pragma unroll
    for (int it = 0; it < 2; it++) {
      const int row = srow + it * 32;
      *(bf16x8*)&Krs[row * LDK + sd0] = pk [it];
      *(bf16x8*)&Kis[row * LDK + sd0] = pki[it];
      *(bf16x8*)&VTr[row * LDK + sd0] = pv [it];
      *(bf16x8*)&VTi[row * LDK + sd0] = pvi[it];
    }
    __syncthreads();   // tiles staged

    if (jt + 1 < jend) {
      const int j0n = (jt + 1) * 64;
      const size_t kb = ((size_t)h * S_LEN + j0n) * HD;
#pragma unroll
      for (int it = 0; it < 2; it++) {
        const int row = srow + it * 32;
        pk [it] = *(const bf16x8*)(Kr  + kb + (size_t)row * HD + sd0);
        pki[it] = *(const bf16x8*)(Ki  + kb + (size_t)row * HD + sd0);
        pv [it] = *(const bf16x8*)(VtR + ((size_t)h * HD + row) * S_LEN + j0n + sd0);
        pvi[it] = *(const bf16x8*)(VtI + ((size_t)h * HD + row) * S_LEN + j0n + sd0);
      }
    }

    // ---- scores ----
    f32x4 k1[4], k2[4], kx[4];
#pragma unroll
    for (int cc = 0; cc < 4; cc++)
#pragma unroll
      for (int r = 0; r < 4; r++) { k1[cc][r] = 0.f; k2[cc][r] = 0.f; kx[cc][r] = 0.f; }
#pragma unroll
    for (int ks = 0; ks < 2; ks++) {
#pragma unroll
      for (int cc = 0; cc < 4; cc++) {
        const int off = (cc * 16 + lcol) * LDK + ks * 32 + quad * 8;
        bf16x8 krf = *(const bf16x8*)&Krs[off];
        bf16x8 kif = *(const bf16x8*)&Kis[off];
        k1[cc] = __builtin_amdgcn_mfma_f32_16x16x32_bf16(qrf[ks], krf, k1[cc], 0, 0, 0);
        k2[cc] = __builtin_amdgcn_mfma_f32_16x16x32_bf16(qif[ks], kif, k2[cc], 0, 0, 0);
        kx[cc] = __builtin_amdgcn_mfma_f32_16x16x32_bf16(qrf[ks], kif, kx[cc], 0, 0, 0);
        kx[cc] = __builtin_amdgcn_mfma_f32_16x16x32_bf16(qif[ks], krf, kx[cc], 0, 0, 0);
      }
    }

    __syncthreads();   // all waves done reading Krs/Kis before Ps overwrites

    // ---- no-max softmax ----
    const bool diag = (jt == itile);
    const int j0 = jt * 64;
#pragma unroll
    for (int r = 0; r < 4; r++) {
      const int prow = (w * 16 + quad * 4 + r) * LDK;
      float rs = 0.f;
#pragma unroll
      for (int cc = 0; cc < 4; cc++) {
        const float a = k1[cc][r] - k2[cc][r];
        const float b = kx[cc][r];
        const float u = fmaf(b, b, a * a);
        const float mag = sqrtf(fmaf(u, c2, 1e-6f));
        float pp = __expf(mag * cfac);
        if (diag) {
          const int gi = i0 + w * 16 + quad * 4 + r;
          const int gj = j0 + cc * 16 + lcol;
          if (gj > gi) pp = 0.f;
        }
        Ps[prow + cc * 16 + lcol] = f2bf(pp);
        rs += pp;
      }
      lsum[r] += rs;
    }

    // ---- PV (wave-private P rows; lgkmcnt covers write->read) ----
#pragma unroll
    for (int ks = 0; ks < 2; ks++) {
      bf16x8 pf = *(const bf16x8*)&Ps[(w * 16 + lcol) * LDK + ks * 32 + quad * 8];
#pragma unroll
      for (int cc = 0; cc < 4; cc++) {
        const int off = (cc * 16 + lcol) * LDK + ks * 32 + quad * 8;
        bf16x8 vrf = *(const bf16x8*)&VTr[off];
        bf16x8 vif = *(const bf16x8*)&VTi[off];
        aOr[cc] = __builtin_amdgcn_mfma_f32_16x16x32_bf16(pf, vrf, aOr[cc], 0, 0, 0);
        aOi[cc] = __builtin_amdgcn_mfma_f32_16x16x32_bf16(pf, vif, aOi[cc], 0, 0, 0);
      }
    }
  }

  // ---- epilogue: UNNORMALIZED bf16 partials + f32 row sums ----
  const size_t SLsz = (size_t)S_LEN * DIM;
#pragma unroll
  for (int r = 0; r < 4; r++) {
    float rs = lsum[r];
#pragma unroll
    for (int off = 1; off < 16; off <<= 1)
      rs += __shfl_xor(rs, off, 16);
    const int row = i0 + w * 16 + quad * 4 + r;
    if (lcol == 0)
      Lp[((size_t)half * NH + h) * S_LEN + row] = rs;
  }
#pragma unroll
  for (int cc = 0; cc < 4; cc++) {
#pragma unroll
    for (int r = 0; r < 4; r++) {
      const int row = i0 + w * 16 + quad * 4 + r;
      const int col = h * HD + cc * 16 + lcol;
      OpR[half * SLsz + (size_t)row * DIM + col] = f2bf(aOr[cc][r]);
      OpI[half * SLsz + (size_t)row * DIM + col] = f2bf(aOi[cc][r]);
    }
  }
}

// ---------------------------------------------------------------------------
// Combine kv-split halves: O = (O0+O1)/(L0+L1), bf16 in/out.
// ---------------------------------------------------------------------------
__global__ __launch_bounds__(256) void combine_kernel(
    const unsigned short* __restrict__ OpR, const unsigned short* __restrict__ OpI,
    const float* __restrict__ Lp,
    unsigned short* __restrict__ Or, unsigned short* __restrict__ Oi)
{
  const size_t SLsz = (size_t)S_LEN * DIM;
  const int idx = blockIdx.x * 256 + threadIdx.x;
  const size_t e0 = (size_t)idx * 8;
  const int s = (int)(e0 >> 10);
  const int col = (int)(e0 & 1023);
  const int h = col >> 6;

  const float L = Lp[(size_t)h * S_LEN + s] + Lp[((size_t)NH + h) * S_LEN + s];
  const float inv = 1.f / L;

  bf16x8 r0 = *(const bf16x8*)(OpR + e0);
  bf16x8 r1 = *(const bf16x8*)(OpR + SLsz + e0);
  bf16x8 i0 = *(const bf16x8*)(OpI + e0);
  bf16x8 i1 = *(const bf16x8*)(OpI + SLsz + e0);

  u16x8 orv, oiv;
#pragma unroll
  for (int j = 0; j < 8; j++) {
    orv[j] = f2bf((bf2f((unsigned short)r0[j]) + bf2f((unsigned short)r1[j])) * inv);
    oiv[j] = f2bf((bf2f((unsigned short)i0[j]) + bf2f((unsigned short)i1[j])) * inv);
  }
  *(u16x8*)(Or + e0) = orv;
  *(u16x8*)(Oi + e0) = oiv;
}

// ---------------------------------------------------------------------------
extern "C" void kernel_launch(void* const* d_in, const int* in_sizes, int n_in,
                              void* d_out, int out_size, void* d_ws, size_t ws_size,
                              hipStream_t stream)
{
  const float* real = (const float*)d_in[0];
  const float* imag = (const float*)d_in[1];
  const float* Wq_r = (const float*)d_in[2];
  const float* bq_r = (const float*)d_in[3];
  const float* Wk_r = (const float*)d_in[4];
  const float* bk_r = (const float*)d_in[5];
  const float* Wv_r = (const float*)d_in[6];
  const float* bv_r = (const float*)d_in[7];
  const float* Wq_i = (const float*)d_in[8];
  const float* bq_i = (const float*)d_in[9];
  const float* Wk_i = (const float*)d_in[10];
  const float* bk_i = (const float*)d_in[11];
  const float* Wv_i = (const float*)d_in[12];
  const float* bv_i = (const float*)d_in[13];
  const float* Wo_r = (const float*)d_in[14];
  const float* bo_r = (const float*)d_in[15];
  const float* Wo_i = (const float*)d_in[16];
  const float* bo_i = (const float*)d_in[17];
  const float* phase = (const float*)d_in[18];
  const float* ent   = (const float*)d_in[19];
  const float* freqs = (const float*)d_in[20];
  const float* p_is  = (const float*)d_in[21];
  const float* p_at  = (const float*)d_in[22];
  const float* p_ce  = (const float*)d_in[23];

  unsigned short* ws = (unsigned short*)d_ws;
  const size_t SL = (size_t)S_LEN * DIM;
  const size_t WL = (size_t)DIM * DIM;

  unsigned short* realb = ws;
  unsigned short* imagb = realb + SL;
  unsigned short* Wb    = imagb + SL;        // 8 x WL
  unsigned short* q_r   = Wb + 8 * WL;
  unsigned short* k_r   = q_r + SL;
  unsigned short* v_r   = k_r + SL;          // [h][d][s]
  unsigned short* q_i   = v_r + SL;
  unsigned short* k_i   = q_i + SL;
  unsigned short* v_i   = k_i + SL;          // [h][d][s]
  unsigned short* OpR   = v_i + SL;          // 2 halves x SL bf16
  unsigned short* OpI   = OpR + 2 * SL;

  float* fbase    = (float*)(OpI + 2 * SL);
  float* biasf    = fbase;                   // 4096
  float* ropeTab  = biasf + 4096;            // 32768 float2
  float* phaseTb2 = ropeTab + 65536;         // 1024 float2
  float* Lp       = phaseTb2 + 2048;         // 2 * NH * S_LEN

  unsigned short* O_r = q_r;   // reuse after flash
  unsigned short* O_i = q_i;

  float* out_r = (float*)d_out;
  float* out_i = out_r + SL;

  // 0. conversions + entangle-fold + tables + folded biases (one dispatch)
  ConvBatch cb;
  cb.src[0] = real; cb.dst[0] = realb; cb.n[0] = (int)SL; cb.fold[0] = 0;
  cb.src[1] = imag; cb.dst[1] = imagb; cb.n[1] = (int)SL; cb.fold[1] = 0;
  const float* wsrc[8] = {Wq_r, Wk_r, Wv_r, Wq_i, Wk_i, Wv_i, Wo_r, Wo_i};
  const int wfold[8]   = {1,    1,    0,    1,    1,    0,    0,    0};
  for (int i = 0; i < 8; i++) {
    cb.src[2 + i] = wsrc[i];
    cb.dst[2 + i] = Wb + (size_t)i * WL;
    cb.n[2 + i] = (int)WL;
    cb.fold[2 + i] = wfold[i];
  }
  conv_kernel<<<dim3(1024, 11), dim3(256), 0, stream>>>(
      cb, ent, freqs, phase, bq_r, bk_r, bq_i, bk_i,
      biasf, (float2*)ropeTab, (float2*)phaseTb2);

  // 1. six projections: Q/K head-major + fused rope (mode 3), V transposed
  BGemm g1;
  g1.A[0] = realb; g1.A[1] = realb; g1.A[2] = realb;
  g1.A[3] = imagb; g1.A[4] = imagb; g1.A[5] = imagb;
  for (int i = 0; i < 6; i++) g1.W[i] = Wb + (size_t)i * WL;
  g1.bias[0] = biasf;        g1.bias[1] = biasf + 1024; g1.bias[2] = bv_r;
  g1.bias[3] = biasf + 2048; g1.bias[4] = biasf + 3072; g1.bias[5] = bv_i;
  g1.C[0] = q_r; g1.C[1] = k_r; g1.C[2] = v_r;
  g1.C[3] = q_i; g1.C[4] = k_i; g1.C[5] = v_i;
  g1.mode[0] = 3; g1.mode[1] = 3; g1.mode[2] = 2;
  g1.mode[3] = 3; g1.mode[4] = 3; g1.mode[5] = 2;
  g1.ropeTab = (const float2*)ropeTab;
  gemm_mfma_kernel<<<dim3(8, 16, 6), dim3(256), 0, stream>>>(g1);

  // 2. flash attention (phase-on-Q folded at load), kv-split -> bf16 partials
  flash_mfma_kernel<<<dim3(1024), dim3(256), 0, stream>>>(
      q_r, q_i, k_r, k_i, v_r, v_i, OpR, OpI, Lp,
      (const float2*)phaseTb2, p_is, p_at, p_ce);

  // 3. combine halves -> bf16 O
  combine_kernel<<<dim3(1024), dim3(256), 0, stream>>>(OpR, OpI, Lp, O_r, O_i);

  // 4. output projections -> fp32 d_out
  BGemm g2 = {};
  g2.A[0] = O_r; g2.A[1] = O_i;
  g2.W[0] = Wb + 6 * WL; g2.W[1] = Wb + 7 * WL;
  g2.bias[0] = bo_r; g2.bias[1] = bo_i;
  g2.C[0] = out_r; g2.C[1] = out_i;
  g2.mode[0] = 0; g2.mode[1] = 0;
  g2.ropeTab = (const float2*)ropeTab;
  gemm_mfma_kernel<<<dim3(8, 16, 2), dim3(256), 0, stream>>>(g2);
}